// Round 6
// baseline (198.131 us; speedup 1.0000x reference)
//
#include <hip/hip_runtime.h>
#include <math.h>

#define ROWLEN 16384
#define BLOCK  512
#define NCHUNK 8              // 8 x float4 = 32 floats / thread; 512*32 = 16384
#define NWAVE  (BLOCK / 64)
#define NMOM   9              // central moments p = 2..10
#define EPSV   1e-10
#define RPB    8              // rows per block (software-pipelined)

// Raw workgroup barrier: waits LDS ops only (lgkmcnt), does NOT drain vmcnt,
// so prefetch global loads stay in flight across the cross-wave reductions.
// (__syncthreads would emit s_waitcnt vmcnt(0) and serialize the pipeline.)
__device__ __forceinline__ void sync_lds()
{
    asm volatile("s_waitcnt lgkmcnt(0)" ::: "memory");
    __builtin_amdgcn_s_barrier();
    asm volatile("" ::: "memory");
}

__global__ __launch_bounds__(BLOCK, 4) void moments_kernel(
    const float* __restrict__ y, float* __restrict__ out)
{
    const int tid  = threadIdx.x;
    const int wave = tid >> 6;
    const int lane = tid & 63;
    const int row0 = blockIdx.x * RPB;

    // parity-double-buffered reduction scratch (avoids extra barriers)
    __shared__ double wsum[2][NWAVE];
    __shared__ double wacc[2][NWAVE][NMOM];

    float4 bufA[NCHUNK], bufB[NCHUNK];   // statically named ping-pong (no dyn idx)

    auto issue = [&](float4 (&buf)[NCHUNK], int row) {
        const float4* yr = reinterpret_cast<const float4*>(y + (size_t)row * ROWLEN);
#pragma unroll
        for (int i = 0; i < NCHUNK; ++i)
            buf[i] = yr[i * BLOCK + tid];
    };

    // Numerics identical to the round-3/5 PASSING kernels.
    auto process = [&](float4 (&cur)[NCHUNK], float4 (&nxt)[NCHUNK],
                       int row, bool do_pref, int par) {
        if (do_pref) issue(nxt, row + 1);   // prefetch next row; stays in flight

        // ---- phase 1: mean ----
        double tsum = 0.0;
#pragma unroll
        for (int i = 0; i < NCHUNK; ++i) {
            float s = (cur[i].x + cur[i].y) + (cur[i].z + cur[i].w);
            tsum += (double)s;
        }
#pragma unroll
        for (int off = 32; off > 0; off >>= 1)
            tsum += __shfl_xor(tsum, off, 64);
        if (lane == 0) wsum[par][wave] = tsum;
        sync_lds();

        double total = 0.0;
#pragma unroll
        for (int w = 0; w < NWAVE; ++w) total += wsum[par][w];
        const double meand = total * (1.0 / (double)ROWLEN);
        const float  meanf = (float)meand;

        // ---- phase 2: central power sums p=2..10 ----
        double acc[NMOM];
#pragma unroll
        for (int p = 0; p < NMOM; ++p) acc[p] = 0.0;

#pragma unroll
        for (int i = 0; i < NCHUNK; ++i) {
            float part[NMOM];
#pragma unroll
            for (int p = 0; p < NMOM; ++p) part[p] = 0.0f;

            const float zs[4] = { cur[i].x - meanf, cur[i].y - meanf,
                                  cur[i].z - meanf, cur[i].w - meanf };
#pragma unroll
            for (int e = 0; e < 4; ++e) {
                const float z = zs[e];
                float zp = z * z;            // p = 2
                part[0] += zp;
#pragma unroll
                for (int p = 1; p < NMOM; ++p) {
                    zp *= z;                 // p = 2 + p
                    part[p] += zp;
                }
            }
#pragma unroll
            for (int p = 0; p < NMOM; ++p) acc[p] += (double)part[p];
        }

#pragma unroll
        for (int p = 0; p < NMOM; ++p) {
#pragma unroll
            for (int off = 32; off > 0; off >>= 1)
                acc[p] += __shfl_xor(acc[p], off, 64);
        }
        if (lane == 0) {
#pragma unroll
            for (int p = 0; p < NMOM; ++p) wacc[par][wave][p] = acc[p];
        }
        sync_lds();

        // ---- epilogue: thread 0 ----
        if (tid == 0) {
            double sums[NMOM];
#pragma unroll
            for (int p = 0; p < NMOM; ++p) {
                double s = 0.0;
#pragma unroll
                for (int w = 0; w < NWAVE; ++w) s += wacc[par][w][p];
                sums[p] = s;
            }

            float* o = out + (size_t)row * 10;

            const double stdv = sqrt(sums[0] / (double)(ROWLEN - 1)) + EPSV;

            const double mean = meand;
            const double sg0 = (mean > 0.0) ? 1.0 : (mean < 0.0 ? -1.0 : 0.0);
            o[0] = (float)(sg0 * log(fabs(mean) + EPSV));

            double sp = stdv;                      // std^1
            for (int p = 0; p < NMOM; ++p) {
                sp *= stdv;                        // std^(p+2)
                const double cm  = sums[p] * (1.0 / (double)ROWLEN);
                const double nrm = cm / (sp + EPSV);
                const double sg  = (nrm > 0.0) ? 1.0 : (nrm < 0.0 ? -1.0 : 0.0);
                double mj = sg * log(fabs(nrm) + EPSV);
                mj = fmin(10.0, fmax(-10.0, mj));
                o[1 + p] = (float)mj;
            }
        }
    };

    issue(bufA, row0);                     // prologue
#pragma unroll 1
    for (int r = 0; r < RPB; r += 2) {
        process(bufA, bufB, row0 + r,     true,               0);
        process(bufB, bufA, row0 + r + 1, (r + 2) < RPB,      1);
    }
}

extern "C" void kernel_launch(void* const* d_in, const int* in_sizes, int n_in,
                              void* d_out, int out_size, void* d_ws, size_t ws_size,
                              hipStream_t stream)
{
    const float* y = (const float*)d_in[0];
    float* out = (float*)d_out;
    const int B = in_sizes[0] / ROWLEN;   // 8192 rows
    moments_kernel<<<B / RPB, BLOCK, 0, stream>>>(y, out);
}

// Round 7
// 157.047 us; speedup vs baseline: 1.2616x; 1.2616x over previous
//
#include <hip/hip_runtime.h>
#include <math.h>

#define ROWLEN 16384
#define BLOCK  256
#define NCHUNK 16             // 16 x float4 = 64 floats / thread; 256*64 = 16384
#define NWAVE  (BLOCK / 64)
#define NMOM   9              // central moments p = 2..10
#define EPSV   1e-10

// No register row-cache: phase 2 re-reads the row. The re-read happens ~1-2us
// after first touch -> served by per-XCD L2 (4 MiB, ~5us eviction horizon) or
// L3 (256 MiB, ~40us horizon). HBM traffic stays ~1x. VGPR drops to ~50 ->
// 6 blocks/CU co-resident (vs 4), memory ops in both phases -> the block-level
// convoy that exposed ~35us of compute in round 5 is broken up.
__global__ __launch_bounds__(BLOCK, 6) void moments_kernel(
    const float* __restrict__ y, float* __restrict__ out)
{
    const int row  = blockIdx.x;
    const int tid  = threadIdx.x;
    const int wave = tid >> 6;
    const int lane = tid & 63;

    const float4* yrow = reinterpret_cast<const float4*>(y + (size_t)row * ROWLEN);

    // ---- phase 1: mean (streaming read #1) ----
    double tsum = 0.0;
#pragma unroll
    for (int i = 0; i < NCHUNK; ++i) {
        const float4 v = yrow[i * BLOCK + tid];
        float s = (v.x + v.y) + (v.z + v.w);
        tsum += (double)s;
    }
#pragma unroll
    for (int off = 32; off > 0; off >>= 1)
        tsum += __shfl_xor(tsum, off, 64);

    __shared__ double wsum[NWAVE];
    if (lane == 0) wsum[wave] = tsum;
    __syncthreads();

    double total = 0.0;
#pragma unroll
    for (int w = 0; w < NWAVE; ++w) total += wsum[w];

    const double meand = total * (1.0 / (double)ROWLEN);
    const float  meanf = (float)meand;

    // ---- phase 2: central power sums p=2..10 (read #2, L2/L3-resident) ----
    double acc[NMOM];
#pragma unroll
    for (int p = 0; p < NMOM; ++p) acc[p] = 0.0;

#pragma unroll
    for (int i = 0; i < NCHUNK; ++i) {
        const float4 v = yrow[i * BLOCK + tid];

        float part[NMOM];
#pragma unroll
        for (int p = 0; p < NMOM; ++p) part[p] = 0.0f;

        const float zs[4] = { v.x - meanf, v.y - meanf,
                              v.z - meanf, v.w - meanf };
#pragma unroll
        for (int e = 0; e < 4; ++e) {
            const float z = zs[e];
            float zp = z * z;            // p = 2
            part[0] += zp;
#pragma unroll
            for (int p = 1; p < NMOM; ++p) {
                zp *= z;                 // p = 2 + p
                part[p] += zp;
            }
        }
        // flush fp32 chunk sums into f64 accumulators (bounds cancellation error)
#pragma unroll
        for (int p = 0; p < NMOM; ++p) acc[p] += (double)part[p];
    }

    // ---- wave reduce each accumulator ----
#pragma unroll
    for (int p = 0; p < NMOM; ++p) {
#pragma unroll
        for (int off = 32; off > 0; off >>= 1)
            acc[p] += __shfl_xor(acc[p], off, 64);
    }

    __shared__ double wacc[NWAVE][NMOM];
    if (lane == 0) {
#pragma unroll
        for (int p = 0; p < NMOM; ++p) wacc[wave][p] = acc[p];
    }
    __syncthreads();

    // ---- epilogue: thread 0 computes the 10 outputs ----
    if (tid == 0) {
        double sums[NMOM];
#pragma unroll
        for (int p = 0; p < NMOM; ++p) {
            double s = 0.0;
#pragma unroll
            for (int w = 0; w < NWAVE; ++w) s += wacc[w][p];
            sums[p] = s;
        }

        float* o = out + (size_t)row * 10;

        // std with ddof=1, + EPS (matches reference)
        const double stdv = sqrt(sums[0] / (double)(ROWLEN - 1)) + EPSV;

        // m0: signed log of |mean|, NOT clipped
        const double mean = meand;
        const double sgn0 = (mean > 0.0) ? 1.0 : (mean < 0.0 ? -1.0 : 0.0);
        o[0] = (float)(sgn0 * log(fabs(mean) + EPSV));

        double sp = stdv;                      // std^1
        for (int p = 0; p < NMOM; ++p) {
            sp *= stdv;                        // std^(p+2)
            const double cm  = sums[p] * (1.0 / (double)ROWLEN);
            const double nrm = cm / (sp + EPSV);
            const double sg  = (nrm > 0.0) ? 1.0 : (nrm < 0.0 ? -1.0 : 0.0);
            double mj = sg * log(fabs(nrm) + EPSV);
            mj = fmin(10.0, fmax(-10.0, mj));
            o[1 + p] = (float)mj;
        }
    }
}

extern "C" void kernel_launch(void* const* d_in, const int* in_sizes, int n_in,
                              void* d_out, int out_size, void* d_ws, size_t ws_size,
                              hipStream_t stream)
{
    const float* y = (const float*)d_in[0];
    float* out = (float*)d_out;
    const int B = in_sizes[0] / ROWLEN;   // 8192 rows
    moments_kernel<<<B, BLOCK, 0, stream>>>(y, out);
}